// Round 13
// baseline (157.296 us; speedup 1.0000x reference)
//
#include <hip/hip_runtime.h>
#include <float.h>

// ReconGraph: out[x][y] = OR over 4 diagonal neighbors of (|d[y+dy][x+dx]-d[y][x]| <= thr),
// OOB neighbor = FLT_MAX (never connects). Output int32 0/1, transposed (out[x*8192+y]).
//
// Round-13: FUSED bit-domain transpose. One kernel, 512(x) x 256(y) tiles:
//  - 8 waves, each a 32-row band: rolling 3-row register stencil, 8 px/lane,
//    2 KB contiguous row loads, results bit-packed into LDS bits[xbyte][y]
//    (stride 260 B -> <=2 lanes/bank on writes AND reads).
//  - one barrier.
//  - store: per output row x, lane ds_read_b32 (4 y-bytes), extract bit x&7,
//    int4 store -> 1 KB contiguous per store instruction. No bitmask HBM traffic.

__device__ __forceinline__ void load_row(const float* __restrict__ d, int y, int x0, int xl,
                                         float* r, float& eL, float& eR) {
    if ((unsigned)y < 8192u) {
        const float4 a = *reinterpret_cast<const float4*>(d + ((size_t)y << 13) + xl);
        const float4 b = *reinterpret_cast<const float4*>(d + ((size_t)y << 13) + xl + 4);
        r[0] = a.x; r[1] = a.y; r[2] = a.z; r[3] = a.w;
        r[4] = b.x; r[5] = b.y; r[6] = b.z; r[7] = b.w;
        eL = (x0 > 0)          ? d[((size_t)y << 13) + x0 - 1]   : FLT_MAX;
        eR = (x0 + 512 < 8192) ? d[((size_t)y << 13) + x0 + 512] : FLT_MAX;
    } else {
#pragma unroll
        for (int i = 0; i < 8; ++i) r[i] = FLT_MAX;
        eL = eR = FLT_MAX;
    }
}

__global__ __launch_bounds__(512, 4)
void recon_fused(const float* __restrict__ d, const float* __restrict__ thrp,
                 int* __restrict__ out) {
    __shared__ unsigned char bits[64][260];   // [x>>3][ylocal], 16.6 KB

    const float thr = thrp[0];
    const int tid  = threadIdx.x;
    const int lane = tid & 63;
    const int wave = tid >> 6;                // 0..7
    const int x0 = blockIdx.x * 512;
    const int y0 = blockIdx.y * 256;
    const int xl = x0 + 8 * lane;             // lane's 8-px base
    const int yb = y0 + wave * 32;            // wave's 32-row band

    // ---- stencil phase: rolling 3-row registers over rows yb-1 .. yb+32
    float rA[8], rB[8], rC[8], rD[8];
    float eA, eB, eC, eD, fA, fB, fC, fD;

    load_row(d, yb - 1, x0, xl, rA, eA, fA);
    load_row(d, yb,     x0, xl, rB, eB, fB);
    load_row(d, yb + 1, x0, xl, rC, eC, fC);

    for (int y = yb; y < yb + 32; ++y) {
        const int yn = y + 2;                 // wave-uniform prefetch guard
        if (yn <= yb + 32) load_row(d, yn, x0, xl, rD, eD, fD);

        // cross-lane x-halo for the diagonal rows
        float lA = __shfl_up(rA[7], 1);   if (lane == 0)  lA = eA;
        float hA = __shfl_down(rA[0], 1); if (lane == 63) hA = fA;
        float lC = __shfl_up(rC[7], 1);   if (lane == 0)  lC = eC;
        float hC = __shfl_down(rC[0], 1); if (lane == 63) hC = fC;

        unsigned byte = 0;
#pragma unroll
        for (int k = 0; k < 8; ++k) {
            const float c  = rB[k];
            const float tl = (k == 0) ? lA : rA[k - 1];
            const float tr = (k == 7) ? hA : rA[k + 1];
            const float bl = (k == 0) ? lC : rC[k - 1];
            const float br = (k == 7) ? hC : rC[k + 1];
            const bool conn = (fabsf(tl - c) <= thr) | (fabsf(tr - c) <= thr) |
                              (fabsf(bl - c) <= thr) | (fabsf(br - c) <= thr);
            byte |= (conn ? 1u : 0u) << k;
        }
        bits[lane][y - y0] = (unsigned char)byte;

#pragma unroll
        for (int i = 0; i < 8; ++i) { rA[i] = rB[i]; rB[i] = rC[i]; rC[i] = rD[i]; }
        eA = eB; eB = eC; eC = eD;
        fA = fB; fB = fC; fC = fD;
    }
    __syncthreads();

    // ---- store phase: wave w -> output rows x0 + w*64 + r, r = 0..63
#pragma unroll 4
    for (int r = 0; r < 64; ++r) {
        const int xloc = wave * 64 + r;       // 0..511
        const int xb   = xloc >> 3;
        const int bit  = xloc & 7;
        const unsigned w32 = *reinterpret_cast<const unsigned*>(&bits[xb][4 * lane]);
        int4 o;
        o.x = (int)((w32 >> (bit))      & 1u);
        o.y = (int)((w32 >> (bit + 8))  & 1u);
        o.z = (int)((w32 >> (bit + 16)) & 1u);
        o.w = (int)((w32 >> (bit + 24)) & 1u);
        *reinterpret_cast<int4*>(out + ((size_t)(x0 + xloc) << 13) + y0 + 4 * lane) = o;
    }
}

extern "C" void kernel_launch(void* const* d_in, const int* in_sizes, int n_in,
                              void* d_out, int out_size, void* d_ws, size_t ws_size,
                              hipStream_t stream) {
    const float* d   = (const float*)d_in[0];
    const float* thr = (const float*)d_in[1];
    int* out = (int*)d_out;
    dim3 grid(16, 32);                        // 512x256 tiles over 8192^2
    recon_fused<<<grid, dim3(512), 0, stream>>>(d, thr, out);
}

// Round 14
// 136.843 us; speedup vs baseline: 1.1495x; 1.1495x over previous
//
#include <hip/hip_runtime.h>
#include <float.h>

// ReconGraph: out[x][y] = OR over 4 diagonal neighbors of (|d[y+dy][x+dx]-d[y][x]| <= thr),
// OOB neighbor = FLT_MAX (never connects). Output int32 0/1, transposed (out[x*8192+y]).
//
// Round-14: two-pass bit-domain transpose (round-12 structure) with occupancy fixes:
//  pass 1: row-order stencil -> bit-packed mask (8 MB) in d_ws. 16-row bands,
//          8192 waves (2048 blocks, 8 blocks/CU = 100% occupancy), rolling 3-row regs.
//  pass 2: mask -> int32 output in output-row order. Wave = 32 x-rows x 256 y:
//          4 uint loads up front, 32 x 1 KB contiguous stores. 8192 waves.
// Fallback (ws too small): round-6 register-stencil kernel (known-good, 154 us).

// ---------------- pass 1 ----------------
__device__ __forceinline__ void load_row(const float* __restrict__ d, int y, int x0, int xl,
                                         float* r, float& eL, float& eR) {
    if ((unsigned)y < 8192u) {
        const float4 a = *reinterpret_cast<const float4*>(d + ((size_t)y << 13) + xl);
        const float4 b = *reinterpret_cast<const float4*>(d + ((size_t)y << 13) + xl + 4);
        r[0] = a.x; r[1] = a.y; r[2] = a.z; r[3] = a.w;
        r[4] = b.x; r[5] = b.y; r[6] = b.z; r[7] = b.w;
        eL = (x0 > 0)          ? d[((size_t)y << 13) + x0 - 1]   : FLT_MAX;
        eR = (x0 + 512 < 8192) ? d[((size_t)y << 13) + x0 + 512] : FLT_MAX;
    } else {
#pragma unroll
        for (int i = 0; i < 8; ++i) r[i] = FLT_MAX;
        eL = eR = FLT_MAX;
    }
}

__global__ __launch_bounds__(256, 8)
void pass1_kernel(const float* __restrict__ d, const float* __restrict__ thrp,
                  unsigned char* __restrict__ bm) {
    const float thr = thrp[0];
    const int tid  = threadIdx.x;
    const int lane = tid & 63;
    const int wid  = blockIdx.x * 4 + (tid >> 6);   // 0..8191
    const int strip = wid & 15;                     // 16 strips of 512 px
    const int band  = wid >> 4;                     // 512 bands of 16 rows
    const int x0 = strip * 512;
    const int yb = band * 16;
    const int xl = x0 + 8 * lane;                   // lane's 8-px base

    float rA[8], rB[8], rC[8], rD[8];               // rows y-1, y, y+1, prefetch y+2
    float eA, eB, eC, eD, fA, fB, fC, fD;

    load_row(d, yb - 1, x0, xl, rA, eA, fA);
    load_row(d, yb,     x0, xl, rB, eB, fB);
    load_row(d, yb + 1, x0, xl, rC, eC, fC);

#pragma unroll 4
    for (int i = 0; i < 16; ++i) {
        const int y  = yb + i;
        const int yn = y + 2;                       // wave-uniform prefetch guard
        if (yn <= yb + 16) load_row(d, yn, x0, xl, rD, eD, fD);

        // cross-lane x-halo for the diagonal rows
        float lA = __shfl_up(rA[7], 1);   if (lane == 0)  lA = eA;
        float hA = __shfl_down(rA[0], 1); if (lane == 63) hA = fA;
        float lC = __shfl_up(rC[7], 1);   if (lane == 0)  lC = eC;
        float hC = __shfl_down(rC[0], 1); if (lane == 63) hC = fC;

        unsigned byte = 0;
#pragma unroll
        for (int k = 0; k < 8; ++k) {
            const float c  = rB[k];
            const float tl = (k == 0) ? lA : rA[k - 1];
            const float tr = (k == 7) ? hA : rA[k + 1];
            const float bl = (k == 0) ? lC : rC[k - 1];
            const float br = (k == 7) ? hC : rC[k + 1];
            const bool conn = (fabsf(tl - c) <= thr) | (fabsf(tr - c) <= thr) |
                              (fabsf(bl - c) <= thr) | (fabsf(br - c) <= thr);
            byte |= (conn ? 1u : 0u) << k;
        }
        bm[(size_t)y * 1024 + (x0 >> 3) + lane] = (unsigned char)byte;

#pragma unroll
        for (int q = 0; q < 8; ++q) { rA[q] = rB[q]; rB[q] = rC[q]; rC[q] = rD[q]; }
        eA = eB; eB = eC; eC = eD;
        fA = fB; fB = fC; fC = fD;
    }
}

// ---------------- pass 2 ----------------
__global__ __launch_bounds__(256, 8)
void pass2_kernel(const unsigned char* __restrict__ bm, int* __restrict__ out) {
    const int tid  = threadIdx.x;
    const int lane = tid & 63;
    const int wid  = blockIdx.x * 4 + (tid >> 6);   // 0..8191
    const int xt = wid >> 5;                        // 256 x-tiles of 32 output rows
    const int yw = wid & 31;                        // 32 y-windows of 256
    const int x0 = xt * 32;
    const int y0 = yw * 256;

    // lane loads 4 mask words: rows y0+4*lane .. +3, byte-cols [4*xt, 4*xt+4)
    unsigned w[4];
#pragma unroll
    for (int j = 0; j < 4; ++j)
        w[j] = *reinterpret_cast<const unsigned*>(bm + (size_t)(y0 + 4 * lane + j) * 1024 + xt * 4);

#pragma unroll
    for (int r = 0; r < 32; ++r) {                  // output row x0+r; bit r of each word
        int4 o;
        o.x = (int)((w[0] >> r) & 1u);
        o.y = (int)((w[1] >> r) & 1u);
        o.z = (int)((w[2] >> r) & 1u);
        o.w = (int)((w[3] >> r) & 1u);
        *reinterpret_cast<int4*>(out + ((size_t)(x0 + r) << 13) + y0 + 4 * lane) = o;
    }
}

// ---------------- fallback (round-6, known-good) ----------------
#define BIG4 make_float4(FLT_MAX, FLT_MAX, FLT_MAX, FLT_MAX)

template<bool EDGE>
__device__ __forceinline__ void recon_body(const float* __restrict__ d, float thr,
                                           int* __restrict__ out, int bx, int by, int tid) {
    const int xq = tid & 15;
    const int yq = tid >> 4;
    const int gx = bx * 64 + 4 * xq;
    const int gy = by * 64 + 4 * yq;
    float s[6][6];
#pragma unroll
    for (int j = 0; j < 6; ++j) {
        const int yy = gy - 1 + j;
        float4 a, b, c;
        if (!EDGE) {
            const float4* p = (const float4*)(d + ((size_t)yy << 13) + gx);
            a = p[-1]; b = p[0]; c = p[1];
        } else {
            const bool yok = (unsigned)yy < 8192u;
            const float4* p = (const float4*)(d + ((size_t)(yok ? yy : 0) << 13) + gx);
            a = (yok && gx >= 4)       ? p[-1] : BIG4;
            b = yok                    ? p[0]  : BIG4;
            c = (yok && gx + 7 < 8192) ? p[1]  : BIG4;
        }
        s[j][0] = a.w; s[j][1] = b.x; s[j][2] = b.y;
        s[j][3] = b.z; s[j][4] = b.w; s[j][5] = c.x;
    }
#pragma unroll
    for (int i = 0; i < 4; ++i) {
        int r[4];
#pragma unroll
        for (int k = 0; k < 4; ++k) {
            const float ctr = s[k + 1][i + 1];
            const bool conn = (fabsf(s[k][i]     - ctr) <= thr) |
                              (fabsf(s[k][i + 2] - ctr) <= thr) |
                              (fabsf(s[k + 2][i]     - ctr) <= thr) |
                              (fabsf(s[k + 2][i + 2] - ctr) <= thr);
            r[k] = conn ? 1 : 0;
        }
        *reinterpret_cast<int4*>(out + ((size_t)(gx + i) << 13) + gy) =
            make_int4(r[0], r[1], r[2], r[3]);
    }
}

__global__ __launch_bounds__(256, 4)
void recon_fallback(const float* __restrict__ d, const float* __restrict__ thrp,
                    int* __restrict__ out) {
    const float thr = thrp[0];
    const int bx = blockIdx.x, by = blockIdx.y;
    if (bx >= 1 && bx <= 126 && by >= 1 && by <= 126)
        recon_body<false>(d, thr, out, bx, by, threadIdx.x);
    else
        recon_body<true>(d, thr, out, bx, by, threadIdx.x);
}

extern "C" void kernel_launch(void* const* d_in, const int* in_sizes, int n_in,
                              void* d_out, int out_size, void* d_ws, size_t ws_size,
                              hipStream_t stream) {
    const float* d   = (const float*)d_in[0];
    const float* thr = (const float*)d_in[1];
    int* out = (int*)d_out;
    const size_t BM_BYTES = (size_t)8192 * 1024;   // 8 MB bit-packed mask

    if (ws_size >= BM_BYTES) {
        unsigned char* bm = (unsigned char*)d_ws;
        pass1_kernel<<<2048, 256, 0, stream>>>(d, thr, bm);
        pass2_kernel<<<2048, 256, 0, stream>>>(bm, out);
    } else {
        recon_fallback<<<dim3(128, 128), 256, 0, stream>>>(d, thr, out);
    }
}

// Round 17
// 101.941 us; speedup vs baseline: 1.5430x; 1.3424x over previous
//
#include <hip/hip_runtime.h>
#include <float.h>

// ReconGraph: out[x][y] = OR over 4 diagonal neighbors of (|d[y+dy][x+dx]-d[y][x]| <= thr),
// OOB neighbor = FLT_MAX (never connects). Output int32 0/1, transposed (out[x*8192+y]).
//
// Round-17 (= round-16 with the pass2 OOB store fixed: chunk offset c*256, was c*1024):
//  pass 1: r12's exact version (32-row bands, 1024 blocks).
//  pass 2 v2: wave = 8 x-rows x 1024 y. Per x-row: 4 consecutive 1 KB nontemporal
//             stores = 4 KB sequential run (DRAM run-length hypothesis).
// Fallback (ws too small): round-6 register-stencil kernel (known-good, 154 us).

typedef int iv4 __attribute__((ext_vector_type(4)));

// ---------------- pass 1 ----------------
__device__ __forceinline__ void load_row(const float* __restrict__ d, int y, int x0, int xl,
                                         float* r, float& eL, float& eR) {
    if ((unsigned)y < 8192u) {
        const float4 a = *reinterpret_cast<const float4*>(d + ((size_t)y << 13) + xl);
        const float4 b = *reinterpret_cast<const float4*>(d + ((size_t)y << 13) + xl + 4);
        r[0] = a.x; r[1] = a.y; r[2] = a.z; r[3] = a.w;
        r[4] = b.x; r[5] = b.y; r[6] = b.z; r[7] = b.w;
        eL = (x0 > 0)          ? d[((size_t)y << 13) + x0 - 1]   : FLT_MAX;
        eR = (x0 + 512 < 8192) ? d[((size_t)y << 13) + x0 + 512] : FLT_MAX;
    } else {
#pragma unroll
        for (int i = 0; i < 8; ++i) r[i] = FLT_MAX;
        eL = eR = FLT_MAX;
    }
}

__global__ __launch_bounds__(256, 4)
void pass1_kernel(const float* __restrict__ d, const float* __restrict__ thrp,
                  unsigned char* __restrict__ bm) {
    const float thr = thrp[0];
    const int tid  = threadIdx.x;
    const int lane = tid & 63;
    const int wid  = blockIdx.x * 4 + (tid >> 6);   // 0..4095
    const int strip = wid & 15;                     // 16 strips of 512 px
    const int band  = wid >> 4;                     // 256 bands of 32 rows
    const int x0 = strip * 512;
    const int yb = band * 32;
    const int xl = x0 + 8 * lane;                   // lane's 8-px base

    float rA[8], rB[8], rC[8], rD[8];               // rows y-1, y, y+1, prefetch y+2
    float eA, eB, eC, eD, fA, fB, fC, fD;

    load_row(d, yb - 1, x0, xl, rA, eA, fA);
    load_row(d, yb,     x0, xl, rB, eB, fB);
    load_row(d, yb + 1, x0, xl, rC, eC, fC);

    for (int y = yb; y < yb + 32; ++y) {
        const int yn = y + 2;                       // wave-uniform prefetch guard
        if (yn <= yb + 32) load_row(d, yn, x0, xl, rD, eD, fD);

        float lA = __shfl_up(rA[7], 1);   if (lane == 0)  lA = eA;
        float hA = __shfl_down(rA[0], 1); if (lane == 63) hA = fA;
        float lC = __shfl_up(rC[7], 1);   if (lane == 0)  lC = eC;
        float hC = __shfl_down(rC[0], 1); if (lane == 63) hC = fC;

        unsigned byte = 0;
#pragma unroll
        for (int k = 0; k < 8; ++k) {
            const float c  = rB[k];
            const float tl = (k == 0) ? lA : rA[k - 1];
            const float tr = (k == 7) ? hA : rA[k + 1];
            const float bl = (k == 0) ? lC : rC[k - 1];
            const float br = (k == 7) ? hC : rC[k + 1];
            const bool conn = (fabsf(tl - c) <= thr) | (fabsf(tr - c) <= thr) |
                              (fabsf(bl - c) <= thr) | (fabsf(br - c) <= thr);
            byte |= (conn ? 1u : 0u) << k;
        }
        bm[(size_t)y * 1024 + (x0 >> 3) + lane] = (unsigned char)byte;

#pragma unroll
        for (int i = 0; i < 8; ++i) { rA[i] = rB[i]; rB[i] = rC[i]; rC[i] = rD[i]; }
        eA = eB; eB = eC; eC = eD;
        fA = fB; fB = fC; fC = fD;
    }
}

// ---------------- pass 2 v2 ----------------
// wave = 8 x-rows x 1024 y. bm read as u32 words (32 x-bits each).
__global__ __launch_bounds__(256, 8)
void pass2_kernel(const unsigned* __restrict__ bm32, int* __restrict__ out) {
    const int tid  = threadIdx.x;
    const int lane = tid & 63;
    const int wid  = blockIdx.x * 4 + (tid >> 6);   // 0..8191
    const int xt = wid >> 3;                        // 1024 x-octets
    const int yw = wid & 7;                         // 8 y-windows of 1024
    const int x0 = xt * 8;
    const int y0 = yw * 1024;
    const int xw = xt >> 2;                         // u32 word column (32 x-bits)
    const int b0 = (xt & 3) * 8;                    // bit base of our 8 x-rows

    // lane loads 16 words: rows y0 + c*256 + 4*lane + j  (c=0..3, j=0..3), col xw
    unsigned w[4][4];
#pragma unroll
    for (int c = 0; c < 4; ++c)
#pragma unroll
        for (int j = 0; j < 4; ++j)
            w[c][j] = bm32[(size_t)(y0 + c * 256 + 4 * lane + j) * 256 + xw];

#pragma unroll
    for (int r = 0; r < 8; ++r) {                   // output row x0+r
        const int bit = b0 + r;
        int* rowp = out + ((size_t)(x0 + r) << 13) + y0 + 4 * lane;
#pragma unroll
        for (int c = 0; c < 4; ++c) {               // 4 consecutive 1 KB chunks
            iv4 o;
            o.x = (int)((w[c][0] >> bit) & 1u);
            o.y = (int)((w[c][1] >> bit) & 1u);
            o.z = (int)((w[c][2] >> bit) & 1u);
            o.w = (int)((w[c][3] >> bit) & 1u);
            __builtin_nontemporal_store(o, reinterpret_cast<iv4*>(rowp + c * 256));
        }
    }
}

// ---------------- fallback (round-6, known-good) ----------------
#define BIG4 make_float4(FLT_MAX, FLT_MAX, FLT_MAX, FLT_MAX)

template<bool EDGE>
__device__ __forceinline__ void recon_body(const float* __restrict__ d, float thr,
                                           int* __restrict__ out, int bx, int by, int tid) {
    const int xq = tid & 15;
    const int yq = tid >> 4;
    const int gx = bx * 64 + 4 * xq;
    const int gy = by * 64 + 4 * yq;
    float s[6][6];
#pragma unroll
    for (int j = 0; j < 6; ++j) {
        const int yy = gy - 1 + j;
        float4 a, b, c;
        if (!EDGE) {
            const float4* p = (const float4*)(d + ((size_t)yy << 13) + gx);
            a = p[-1]; b = p[0]; c = p[1];
        } else {
            const bool yok = (unsigned)yy < 8192u;
            const float4* p = (const float4*)(d + ((size_t)(yok ? yy : 0) << 13) + gx);
            a = (yok && gx >= 4)       ? p[-1] : BIG4;
            b = yok                    ? p[0]  : BIG4;
            c = (yok && gx + 7 < 8192) ? p[1]  : BIG4;
        }
        s[j][0] = a.w; s[j][1] = b.x; s[j][2] = b.y;
        s[j][3] = b.z; s[j][4] = b.w; s[j][5] = c.x;
    }
#pragma unroll
    for (int i = 0; i < 4; ++i) {
        int r[4];
#pragma unroll
        for (int k = 0; k < 4; ++k) {
            const float ctr = s[k + 1][i + 1];
            const bool conn = (fabsf(s[k][i]     - ctr) <= thr) |
                              (fabsf(s[k][i + 2] - ctr) <= thr) |
                              (fabsf(s[k + 2][i]     - ctr) <= thr) |
                              (fabsf(s[k + 2][i + 2] - ctr) <= thr);
            r[k] = conn ? 1 : 0;
        }
        *reinterpret_cast<int4*>(out + ((size_t)(gx + i) << 13) + gy) =
            make_int4(r[0], r[1], r[2], r[3]);
    }
}

__global__ __launch_bounds__(256, 4)
void recon_fallback(const float* __restrict__ d, const float* __restrict__ thrp,
                    int* __restrict__ out) {
    const float thr = thrp[0];
    const int bx = blockIdx.x, by = blockIdx.y;
    if (bx >= 1 && bx <= 126 && by >= 1 && by <= 126)
        recon_body<false>(d, thr, out, bx, by, threadIdx.x);
    else
        recon_body<true>(d, thr, out, bx, by, threadIdx.x);
}

extern "C" void kernel_launch(void* const* d_in, const int* in_sizes, int n_in,
                              void* d_out, int out_size, void* d_ws, size_t ws_size,
                              hipStream_t stream) {
    const float* d   = (const float*)d_in[0];
    const float* thr = (const float*)d_in[1];
    int* out = (int*)d_out;
    const size_t BM_BYTES = (size_t)8192 * 1024;   // 8 MB bit-packed mask

    if (ws_size >= BM_BYTES) {
        unsigned char* bm = (unsigned char*)d_ws;
        pass1_kernel<<<1024, 256, 0, stream>>>(d, thr, bm);
        pass2_kernel<<<2048, 256, 0, stream>>>((const unsigned*)bm, out);
    } else {
        recon_fallback<<<dim3(128, 128), 256, 0, stream>>>(d, thr, out);
    }
}